// Round 2
// baseline (1285.152 us; speedup 1.0000x reference)
//
#include <hip/hip_runtime.h>

#define G    256
#define CCH  16
#define HIDN 128
#define TS   16
#define LDSW 19   // padded LDS row stride (18 used), breaks bank aliasing

#define XS_FLOATS  (CCH * 18 * LDSW)                 // 5472 floats (21.9 KB)
#define W1_FLOATS  (HIDN * 48)                       // 6144
#define W2T_FLOATS (HIDN * CCH)                      // 2048
#define WTOT       (W1_FLOATS + W2T_FLOATS + HIDN)   // 8320 floats (33.3 KB)
#define LDS_FLOATS (WTOT > XS_FLOATS ? WTOT : XS_FLOATS)

// ---------------- Kernel 1: conv + MLP + residual + pre_life ----------------
// out[b,c,h,w] = pre_life ? x + (w2 @ relu(w1 @ y + b1)) * um : 0
// alpha_new[b,h,w] = pristine x_new alpha (pre-mask) for kernel 2's maxpool
// Weights are staged into LDS (overlaid on the xs tile after perception) to
// kill the per-k scalar-cache thrash: w1 row = 12 ds_read_b128 broadcasts,
// w2^T row = 4 ds_read_b128 broadcasts (transposed at staging time).
__global__ __launch_bounds__(256, 4) void nca_compute(
    const float* __restrict__ x, const float* __restrict__ w1,
    const float* __restrict__ b1, const float* __restrict__ w2,
    const float* __restrict__ um, float* __restrict__ out,
    float* __restrict__ alpha_new)
{
    __shared__ __align__(16) float lds[LDS_FLOATS];
    const int tx = threadIdx.x, ty = threadIdx.y;
    const int bx = blockIdx.x * TS, by = blockIdx.y * TS, b = blockIdx.z;
    const int tid = ty * TS + tx;

    // ---- stage 18x18 halo tile of all 16 channels into LDS (zero-pad OOB) ----
    const float* xb = x + (size_t)b * CCH * G * G;
    for (int i = tid; i < CCH * 18 * 18; i += 256) {
        int c   = i / (18 * 18);
        int rem = i % (18 * 18);
        int r   = rem / 18;
        int col = rem % 18;
        int gy = by + r - 1, gx = bx + col - 1;
        float v = 0.f;
        if (gy >= 0 && gy < G && gx >= 0 && gx < G)
            v = xb[(size_t)c * G * G + (size_t)gy * G + gx];
        lds[c * (18 * LDSW) + r * LDSW + col] = v;
    }
    __syncthreads();

    // ---- perception vector y[48]: per channel [identity, sobel_x/8, sobel_y/8] ----
    float y[48];
    #pragma unroll
    for (int c = 0; c < CCH; c++) {
        const float* xc = lds + c * (18 * LDSW);
        float a00 = xc[(ty    ) * LDSW + tx    ];
        float a01 = xc[(ty    ) * LDSW + tx + 1];
        float a02 = xc[(ty    ) * LDSW + tx + 2];
        float a10 = xc[(ty + 1) * LDSW + tx    ];
        float a11 = xc[(ty + 1) * LDSW + tx + 1];
        float a12 = xc[(ty + 1) * LDSW + tx + 2];
        float a20 = xc[(ty + 2) * LDSW + tx    ];
        float a21 = xc[(ty + 2) * LDSW + tx + 1];
        float a22 = xc[(ty + 2) * LDSW + tx + 2];
        y[3 * c]     = a11;
        y[3 * c + 1] = ((a02 - a00) + 2.f * (a12 - a10) + (a22 - a20)) * 0.125f;
        y[3 * c + 2] = ((a20 - a00) + 2.f * (a21 - a01) + (a22 - a02)) * 0.125f;
    }

    // ---- pre_life: 3x3 maxpool of alpha (channel 3) from the staged halo ----
    // zero-pad is equivalent to -inf pad here since the threshold 0.1 > 0.
    float mp = -1e30f;
    {
        const float* xa = lds + 3 * (18 * LDSW);
        #pragma unroll
        for (int dy = 0; dy < 3; dy++)
            #pragma unroll
            for (int dx = 0; dx < 3; dx++)
                mp = fmaxf(mp, xa[(ty + dy) * LDSW + tx + dx]);
    }
    const bool pre = mp > 0.1f;
    const int gy = by + ty, gx = bx + tx;
    const float m = um[(size_t)b * G * G + (size_t)gy * G + gx];

    __syncthreads();   // xs fully consumed; safe to overwrite with weights

    // ---- stage weights into LDS: w1 rows contiguous, w2 transposed, b1 ----
    {
        const float4* w1v = (const float4*)w1;
        float4* dst = (float4*)lds;
        for (int i = tid; i < W1_FLOATS / 4; i += 256) dst[i] = w1v[i];
        float* ws2t = lds + W1_FLOATS;
        for (int i = tid; i < W2T_FLOATS; i += 256) {
            int c = i >> 7, k = i & 127;      // w2 is [C][HIDN]
            ws2t[k * CCH + c] = w2[i];
        }
        float* wb1 = lds + W1_FLOATS + W2T_FLOATS;
        for (int i = tid; i < HIDN; i += 256) wb1[i] = b1[i];
    }
    __syncthreads();

    const float* ws2t = lds + W1_FLOATS;
    const float* wb1  = lds + W1_FLOATS + W2T_FLOATS;

    float acc[CCH];
    #pragma unroll
    for (int c = 0; c < CCH; c++) acc[c] = 0.f;

    // ---- MLP: all weight reads are wave-uniform LDS broadcasts ----
    for (int k = 0; k < HIDN; k++) {
        const float4* w1r = (const float4*)(lds + k * 48);   // 192B-aligned
        float h0 = wb1[k], h1 = 0.f, h2 = 0.f, h3 = 0.f;     // 4-way dep break
        #pragma unroll
        for (int q = 0; q < 12; q++) {
            float4 w = w1r[q];
            h0 = fmaf(w.x, y[4 * q    ], h0);
            h1 = fmaf(w.y, y[4 * q + 1], h1);
            h2 = fmaf(w.z, y[4 * q + 2], h2);
            h3 = fmaf(w.w, y[4 * q + 3], h3);
        }
        float hk = fmaxf((h0 + h1) + (h2 + h3), 0.f);
        const float4* w2r = (const float4*)(ws2t + k * CCH); // 64B-aligned
        #pragma unroll
        for (int q = 0; q < 4; q++) {
            float4 w = w2r[q];
            acc[4 * q    ] = fmaf(w.x, hk, acc[4 * q    ]);
            acc[4 * q + 1] = fmaf(w.y, hk, acc[4 * q + 1]);
            acc[4 * q + 2] = fmaf(w.z, hk, acc[4 * q + 2]);
            acc[4 * q + 3] = fmaf(w.w, hk, acc[4 * q + 3]);
        }
    }

    // ---- epilogue: residual (center = y[3c]), pre_life mask, pristine alpha ----
    const size_t pix   = (size_t)gy * G + gx;
    const size_t obase = (size_t)b * CCH * G * G + pix;
    #pragma unroll
    for (int c = 0; c < CCH; c++) {
        float xn = y[3 * c] + acc[c] * m;
        if (c == 3) alpha_new[(size_t)b * G * G + pix] = xn;  // pre-mask copy
        out[obase + (size_t)c * G * G] = pre ? xn : 0.f;
    }
}

// ---------------- Kernel 2: post_life mask ----------------
// if maxpool3x3(alpha_new) <= 0.1: zero the pixel. Pixels already zeroed by
// kernel 1 (!pre_life) may be re-zeroed — idempotent, so no pre_life read.
__global__ __launch_bounds__(256) void nca_mask(
    const float* __restrict__ alpha_new, float* __restrict__ out)
{
    __shared__ float na[18 * LDSW];
    const int tx = threadIdx.x, ty = threadIdx.y;
    const int bx = blockIdx.x * TS, by = blockIdx.y * TS, b = blockIdx.z;
    const int tid = ty * TS + tx;

    const float* nb = alpha_new + (size_t)b * G * G;
    for (int i = tid; i < 18 * 18; i += 256) {
        int r = i / 18, col = i % 18;
        int gy = by + r - 1, gx = bx + col - 1;
        float vn = -1e30f;
        if (gy >= 0 && gy < G && gx >= 0 && gx < G)
            vn = nb[(size_t)gy * G + gx];
        na[r * LDSW + col] = vn;
    }
    __syncthreads();

    float mn = -1e30f;
    #pragma unroll
    for (int dy = 0; dy < 3; dy++)
        #pragma unroll
        for (int dx = 0; dx < 3; dx++)
            mn = fmaxf(mn, na[(ty + dy) * LDSW + tx + dx]);

    if (!(mn > 0.1f)) {
        const size_t obase = (size_t)b * CCH * G * G + (size_t)(by + ty) * G + (bx + tx);
        #pragma unroll
        for (int c = 0; c < CCH; c++)
            out[obase + (size_t)c * G * G] = 0.f;
    }
}

extern "C" void kernel_launch(void* const* d_in, const int* in_sizes, int n_in,
                              void* d_out, int out_size, void* d_ws, size_t ws_size,
                              hipStream_t stream) {
    const float* x  = (const float*)d_in[0];
    const float* w1 = (const float*)d_in[1];
    const float* b1 = (const float*)d_in[2];
    const float* w2 = (const float*)d_in[3];
    const float* um = (const float*)d_in[4];
    float* out = (float*)d_out;
    float* alpha_new = (float*)d_ws;   // B*G*G floats = 8.4 MB scratch

    dim3 grid(G / TS, G / TS, 32);
    dim3 block(TS, TS);
    nca_compute<<<grid, block, 0, stream>>>(x, w1, b1, w2, um, out, alpha_new);
    nca_mask<<<grid, block, 0, stream>>>(alpha_new, out);
}

// Round 3
// 986.758 us; speedup vs baseline: 1.3024x; 1.3024x over previous
//
#include <hip/hip_runtime.h>

#define G    256
#define CCH  16
#define HIDN 128
#define TSX  16
#define TSY  32          // 2 pixels per thread, vertical pair (ty, ty+16)
#define XROWS 34         // TSY + 2 halo rows
#define LDSW 19          // padded LDS row stride (18 used), breaks bank aliasing
#define CSTRIDE (XROWS * LDSW)              // 646 floats per channel
#define XS_FLOATS (CCH * CSTRIDE)           // 10336 floats
#define W2T_FLOATS (HIDN * CCH)             // 2048 floats
// total LDS: 10336 + 2048 = 12384 floats = 49.5 KB -> 3 blocks/CU

// ---------------- Kernel 1: conv + MLP + residual + pre_life ----------------
// 2 px/thread amortizes the per-k weight fetch over 2x FMA work.
// Weight pipes split: w1,b1 -> scalar K$ (uniform s_load, 3 lines/k);
//                     w2^T  -> LDS (4 uniform ds_read_b128/k, ~44cyc/k/wave,
//                              under the 256cyc/k VALU issue time).
__global__ __launch_bounds__(256) void nca_compute(
    const float* __restrict__ x, const float* __restrict__ w1,
    const float* __restrict__ b1, const float* __restrict__ w2,
    const float* __restrict__ um, float* __restrict__ out,
    float* __restrict__ alpha_new)
{
    __shared__ __align__(16) float lds[XS_FLOATS + W2T_FLOATS];
    float* __restrict__ w2t = lds + XS_FLOATS;   // [k][c], 64B rows

    const int tx = threadIdx.x, ty = threadIdx.y;
    const int bx = blockIdx.x * TSX, by = blockIdx.y * TSY, b = blockIdx.z;
    const int tid = ty * TSX + tx;

    // ---- stage 34x18 halo tile of all 16 channels (zero-pad OOB) ----
    const float* xb = x + (size_t)b * CCH * G * G;
    for (int i = tid; i < CCH * XROWS * 18; i += 256) {
        int c   = i / (XROWS * 18);
        int rem = i % (XROWS * 18);
        int r   = rem / 18;
        int col = rem % 18;
        int gy = by + r - 1, gx = bx + col - 1;
        float v = 0.f;
        if (gy >= 0 && gy < G && gx >= 0 && gx < G)
            v = xb[(size_t)c * G * G + (size_t)gy * G + gx];
        lds[c * CSTRIDE + r * LDSW + col] = v;
    }
    // ---- stage w2^T (coalesced global read, transposed LDS write) ----
    for (int i = tid; i < W2T_FLOATS; i += 256) {
        int c = i >> 7, k = i & 127;          // w2 is [C][HIDN]
        w2t[k * CCH + c] = w2[i];
    }
    __syncthreads();

    // ---- update-mask loads early (hide HBM latency under perception) ----
    const int gy0 = by + ty, gy1 = by + ty + 16, gx0 = bx + tx;
    const float m0 = um[(size_t)b * G * G + (size_t)gy0 * G + gx0];
    const float m1 = um[(size_t)b * G * G + (size_t)gy1 * G + gx0];

    // ---- perception y[2][48]: per channel [identity, sobel_x/8, sobel_y/8] ----
    float yv[2][48];
    #pragma unroll
    for (int px = 0; px < 2; px++) {
        const int ry = ty + px * 16;
        #pragma unroll
        for (int c = 0; c < CCH; c++) {
            const float* xc = &lds[c * CSTRIDE + ry * LDSW + tx];
            float a00 = xc[0],        a01 = xc[1],            a02 = xc[2];
            float a10 = xc[LDSW],     a11 = xc[LDSW + 1],     a12 = xc[LDSW + 2];
            float a20 = xc[2 * LDSW], a21 = xc[2 * LDSW + 1], a22 = xc[2 * LDSW + 2];
            yv[px][3 * c]     = a11;
            yv[px][3 * c + 1] = ((a02 - a00) + 2.f * (a12 - a10) + (a22 - a20)) * 0.125f;
            yv[px][3 * c + 2] = ((a20 - a00) + 2.f * (a21 - a01) + (a22 - a02)) * 0.125f;
        }
    }

    // ---- pre_life: 3x3 maxpool of alpha (ch 3); zero-pad ok since 0.1 > 0 ----
    bool pre[2];
    #pragma unroll
    for (int px = 0; px < 2; px++) {
        const float* xa = &lds[3 * CSTRIDE + (ty + px * 16) * LDSW + tx];
        float mp = -1e30f;
        #pragma unroll
        for (int dy = 0; dy < 3; dy++)
            #pragma unroll
            for (int dx = 0; dx < 3; dx++)
                mp = fmaxf(mp, xa[dy * LDSW + dx]);
        pre[px] = mp > 0.1f;
    }

    float acc[2][CCH];
    #pragma unroll
    for (int c = 0; c < CCH; c++) { acc[0][c] = 0.f; acc[1][c] = 0.f; }

    // ---- MLP: 128 FMA/thread/k vs 3 scalar lines + 4 LDS b128 per k ----
    for (int k = 0; k < HIDN; k++) {
        const float4* w1r = (const float4*)(w1 + k * 48);   // uniform -> s_load
        const float bk = b1[k];
        float h0a = bk, h0b = 0.f, h0c = 0.f, h0d = 0.f;
        float h1a = bk, h1b = 0.f, h1c = 0.f, h1d = 0.f;
        #pragma unroll
        for (int q = 0; q < 12; q++) {
            float4 w = w1r[q];
            h0a = fmaf(w.x, yv[0][4 * q    ], h0a);
            h0b = fmaf(w.y, yv[0][4 * q + 1], h0b);
            h0c = fmaf(w.z, yv[0][4 * q + 2], h0c);
            h0d = fmaf(w.w, yv[0][4 * q + 3], h0d);
            h1a = fmaf(w.x, yv[1][4 * q    ], h1a);
            h1b = fmaf(w.y, yv[1][4 * q + 1], h1b);
            h1c = fmaf(w.z, yv[1][4 * q + 2], h1c);
            h1d = fmaf(w.w, yv[1][4 * q + 3], h1d);
        }
        const float hk0 = fmaxf((h0a + h0b) + (h0c + h0d), 0.f);
        const float hk1 = fmaxf((h1a + h1b) + (h1c + h1d), 0.f);
        const float4* w2r = (const float4*)(w2t + k * CCH); // 64B-aligned row
        #pragma unroll
        for (int q = 0; q < 4; q++) {
            float4 w = w2r[q];
            acc[0][4 * q    ] = fmaf(w.x, hk0, acc[0][4 * q    ]);
            acc[0][4 * q + 1] = fmaf(w.y, hk0, acc[0][4 * q + 1]);
            acc[0][4 * q + 2] = fmaf(w.z, hk0, acc[0][4 * q + 2]);
            acc[0][4 * q + 3] = fmaf(w.w, hk0, acc[0][4 * q + 3]);
            acc[1][4 * q    ] = fmaf(w.x, hk1, acc[1][4 * q    ]);
            acc[1][4 * q + 1] = fmaf(w.y, hk1, acc[1][4 * q + 1]);
            acc[1][4 * q + 2] = fmaf(w.z, hk1, acc[1][4 * q + 2]);
            acc[1][4 * q + 3] = fmaf(w.w, hk1, acc[1][4 * q + 3]);
        }
    }

    // ---- epilogue: residual (center = yv[px][3c]), pre_life, pristine alpha ----
    #pragma unroll
    for (int px = 0; px < 2; px++) {
        const int gy = (px == 0) ? gy0 : gy1;
        const float m = (px == 0) ? m0 : m1;
        const size_t pix   = (size_t)gy * G + gx0;
        const size_t obase = (size_t)b * CCH * G * G + pix;
        #pragma unroll
        for (int c = 0; c < CCH; c++) {
            float xn = yv[px][3 * c] + acc[px][c] * m;
            if (c == 3) alpha_new[(size_t)b * G * G + pix] = xn;  // pre-mask copy
            out[obase + (size_t)c * G * G] = pre[px] ? xn : 0.f;
        }
    }
}

// ---------------- Kernel 2: post_life mask ----------------
// if maxpool3x3(alpha_new) <= 0.1: zero the pixel. Re-zeroing pixels already
// zeroed by kernel 1 (!pre_life) is idempotent -> no read of x needed.
__global__ __launch_bounds__(256) void nca_mask(
    const float* __restrict__ alpha_new, float* __restrict__ out)
{
    __shared__ float na[18 * LDSW];
    const int tx = threadIdx.x, ty = threadIdx.y;
    const int bx = blockIdx.x * 16, by = blockIdx.y * 16, b = blockIdx.z;
    const int tid = ty * 16 + tx;

    const float* nb = alpha_new + (size_t)b * G * G;
    for (int i = tid; i < 18 * 18; i += 256) {
        int r = i / 18, col = i % 18;
        int gy = by + r - 1, gx = bx + col - 1;
        float vn = -1e30f;
        if (gy >= 0 && gy < G && gx >= 0 && gx < G)
            vn = nb[(size_t)gy * G + gx];
        na[r * LDSW + col] = vn;
    }
    __syncthreads();

    float mn = -1e30f;
    #pragma unroll
    for (int dy = 0; dy < 3; dy++)
        #pragma unroll
        for (int dx = 0; dx < 3; dx++)
            mn = fmaxf(mn, na[(ty + dy) * LDSW + tx + dx]);

    if (!(mn > 0.1f)) {
        const size_t obase = (size_t)b * CCH * G * G + (size_t)(by + ty) * G + (bx + tx);
        #pragma unroll
        for (int c = 0; c < CCH; c++)
            out[obase + (size_t)c * G * G] = 0.f;
    }
}

extern "C" void kernel_launch(void* const* d_in, const int* in_sizes, int n_in,
                              void* d_out, int out_size, void* d_ws, size_t ws_size,
                              hipStream_t stream) {
    const float* x  = (const float*)d_in[0];
    const float* w1 = (const float*)d_in[1];
    const float* b1 = (const float*)d_in[2];
    const float* w2 = (const float*)d_in[3];
    const float* um = (const float*)d_in[4];
    float* out = (float*)d_out;
    float* alpha_new = (float*)d_ws;   // B*G*G floats = 8.4 MB scratch

    dim3 gridC(G / TSX, G / TSY, 32);  // (16, 8, 32)
    dim3 blockC(TSX, 16);              // 256 threads, 2 px each
    nca_compute<<<gridC, blockC, 0, stream>>>(x, w1, b1, w2, um, out, alpha_new);

    dim3 gridM(G / 16, G / 16, 32);
    dim3 blockM(16, 16);
    nca_mask<<<gridM, blockM, 0, stream>>>(alpha_new, out);
}